// Round 3
// baseline (803.370 us; speedup 1.0000x reference)
//
#include <hip/hip_runtime.h>
#include <math.h>

#define NU_F 0.0031830988618379067f

typedef __bf16 bf16x8 __attribute__((ext_vector_type(8)));
typedef float  f32x4  __attribute__((ext_vector_type(4)));

__device__ __forceinline__ float fast_tanh(float z) {
    float e = __expf(2.0f * z);
    return 1.0f - 2.0f / (e + 1.0f);
}

// Pack truncated-bf16 hi halves of (a,b) -> one u32: {b.hi16, a.hi16}
__device__ __forceinline__ unsigned pack_hi(float a, float b) {
    return __builtin_amdgcn_perm(__float_as_uint(b), __float_as_uint(a), 0x07060302u);
}
// Pack bf16(lo) of (a,b) where lo = v - trunc16(v)
__device__ __forceinline__ unsigned pack_lo(float a, float b) {
    float ra = a - __uint_as_float(__float_as_uint(a) & 0xffff0000u);
    float rb = b - __uint_as_float(__float_as_uint(b) & 0xffff0000u);
    __bf16 la = (__bf16)ra, lb = (__bf16)rb;
    unsigned ua = (unsigned)*(unsigned short*)&la;
    unsigned ub = (unsigned)*(unsigned short*)&lb;
    return __builtin_amdgcn_perm(ub, ua, 0x05040100u);
}

// ---------------------------------------------------------------------------
// Prep: W_hid fp32 [7][128(k)][128(c)] -> interleaved hi/lo bf16 B-fragments.
// Element: (l*8+nt)*4096 + lane*64 + hl*32 + ks*8 + jj
//   k = ks*32 + q*8 + jj, lane = q*16 + nn
//   channel map: nt = ((c>>5)<<1)|(c&1), nn = (c>>1)&15  ->  c = wv*32+nn*2+j
// ---------------------------------------------------------------------------
__global__ void prep_wfrag(const float* __restrict__ Whid, __bf16* __restrict__ wcf)
{
    int t = blockIdx.x * 256 + threadIdx.x;   // 0 .. 114687
    const int l = t >> 14;
    const int r = t & 16383;
    const int k = r >> 7;
    const int c = r & 127;
    const float v = Whid[t];
    const __bf16 hi = (__bf16)v;              // RNE hi (prep runs once; free)
    const __bf16 lo = (__bf16)(v - (float)hi);
    const int ks = k >> 5, q = (k >> 3) & 3, jj = k & 7;
    const int nt = ((c >> 5) << 1) | (c & 1);
    const int nn = (c >> 1) & 15;
    const int lane = q * 16 + nn;
    const int base = ((l * 8 + nt) * 64 + lane) * 64 + ks * 8 + jj;
    wcf[base]      = hi;
    wcf[base + 32] = lo;
}

// ---------------------------------------------------------------------------
// Fused kernel. Blocks 0..8191: 16 deriv points (jet states v,vx,vt,vxx as
// 4 M-tiles). Blocks 8192..8319: 64 value-only points (4 M-tiles of points).
// H in LDS as packed u32 rows [64][68] (64 k-dwords + 4 pad), hi and lo.
// GEMM: Z[row][c] = sum_k H[row][k]*W[k][c], mfma_f32_16x16x32_bf16,
// hi/lo split (3 terms; vxx state uses 2 -- its lo rows stay zero).
// Epilogue: D col = lane&15 -> channel pair (wv*32+lm*2 + {0,1}) -> packed
// b32 writes at dword col wv*16+lm (lane-stride 1: conflict-free).
// ---------------------------------------------------------------------------
#define HR 68

#define MFMA(A, B, C) __builtin_amdgcn_mfma_f32_16x16x32_bf16((A), (B), (C), 0, 0, 0)

__global__ __launch_bounds__(256, 4)
void pinn_fused(const float* __restrict__ xf,
                const float* __restrict__ x0,  const float* __restrict__ xbl,
                const float* __restrict__ xbr,
                const float* __restrict__ Win,  const float* __restrict__ bin,
                const float* __restrict__ bhid,
                const float* __restrict__ Wout, const float* __restrict__ bout,
                const __bf16* __restrict__ wcf,
                float* __restrict__ out)
{
    __shared__ unsigned Hhi[64 * HR];
    __shared__ unsigned Hlo[64 * HR];
    __shared__ float xpt[128];
    __shared__ float pbuf[256];
    __shared__ float dots[64];

    const int tid  = threadIdx.x;
    const int lane = tid & 63;
    const int wv   = tid >> 6;
    const int lm   = lane & 15;
    const int lq   = lane >> 4;
    const int blk  = blockIdx.x;
    const bool isv = (blk >= 8192);

    if (!isv) {
        if (tid < 32) xpt[tid] = xf[blk * 32 + tid];
    } else {
        const int vb = blk - 8192;
        const float* src = (vb < 64) ? (x0 + vb * 128)
                         : (vb < 96) ? (xbl + (vb - 64) * 128)
                                     : (xbr + (vb - 96) * 128);
        if (tid < 128) xpt[tid] = src[tid];
    }
    __syncthreads();

    // ---- input layer: thread owns channel pair c0=2*(tid&63) ----
    const int cp = tid & 63;
    {
        const float2 w01 = *(const float2*)&Win[cp * 2];
        const float2 w11 = *(const float2*)&Win[128 + cp * 2];
        const float2 bb  = *(const float2*)&bin[cp * 2];
        if (!isv) {
            const int p0 = (tid >> 6) * 4;
            #pragma unroll
            for (int i = 0; i < 4; ++i) {
                const int p = p0 + i;
                const float x = xpt[2 * p], tt = xpt[2 * p + 1];
                const float za = fmaf(x, w01.x, fmaf(tt, w11.x, bb.x));
                const float zb = fmaf(x, w01.y, fmaf(tt, w11.y, bb.y));
                const float ya = fast_tanh(za), yb = fast_tanh(zb);
                const float da = 1.f - ya * ya, db = 1.f - yb * yb;
                const float v1a = da * w01.x, v1b = db * w01.y;
                const float v2a = da * w11.x, v2b = db * w11.y;
                const float v3a = -2.f * ya * da * w01.x * w01.x;
                const float v3b = -2.f * yb * db * w01.y * w01.y;
                Hhi[(0 * 16 + p) * HR + cp] = pack_hi(ya, yb);
                Hhi[(1 * 16 + p) * HR + cp] = pack_hi(v1a, v1b);
                Hhi[(2 * 16 + p) * HR + cp] = pack_hi(v2a, v2b);
                Hhi[(3 * 16 + p) * HR + cp] = pack_hi(v3a, v3b);
                Hlo[(0 * 16 + p) * HR + cp] = pack_lo(ya, yb);
                Hlo[(1 * 16 + p) * HR + cp] = pack_lo(v1a, v1b);
                Hlo[(2 * 16 + p) * HR + cp] = pack_lo(v2a, v2b);
                Hlo[(3 * 16 + p) * HR + cp] = 0u;   // stays 0 all layers
            }
        } else {
            const int p0 = (tid >> 6) * 16;
            #pragma unroll
            for (int i = 0; i < 16; ++i) {
                const int p = p0 + i;
                const float x = xpt[2 * p], tt = xpt[2 * p + 1];
                const float za = fmaf(x, w01.x, fmaf(tt, w11.x, bb.x));
                const float zb = fmaf(x, w01.y, fmaf(tt, w11.y, bb.y));
                const float ya = fast_tanh(za), yb = fast_tanh(zb);
                Hhi[p * HR + cp] = pack_hi(ya, yb);
                Hlo[p * HR + cp] = pack_lo(ya, yb);
            }
        }
    }
    __syncthreads();

    // B-fragment pointers: per-lane contiguous 64 B (hi 4 frags, lo 4 frags)
    const __bf16* p0w = wcf + (wv * 2) * 4096 + lane * 64;
    const __bf16* p1w = p0w + 4096;
    const float2* bh2 = (const float2*)bhid + (wv * 16 + lm);
    const int wc = wv * 16 + lm;   // epilogue dword column

    if (!isv) {
        // ================= derivative path =================
        for (int l = 0; l < 7; ++l) {
            f32x4 acc[4][2];
            #pragma unroll
            for (int s = 0; s < 4; ++s)
                #pragma unroll
                for (int j = 0; j < 2; ++j) acc[s][j] = (f32x4){0.f, 0.f, 0.f, 0.f};

            #pragma unroll
            for (int ks = 0; ks < 4; ++ks) {
                const int ro = ks * 16 + lq * 4;
                const bf16x8 ah0 = *(const bf16x8*)&Hhi[(0 * 16 + lm) * HR + ro];
                const bf16x8 ah1 = *(const bf16x8*)&Hhi[(1 * 16 + lm) * HR + ro];
                const bf16x8 ah2 = *(const bf16x8*)&Hhi[(2 * 16 + lm) * HR + ro];
                const bf16x8 ah3 = *(const bf16x8*)&Hhi[(3 * 16 + lm) * HR + ro];
                const bf16x8 al0 = *(const bf16x8*)&Hlo[(0 * 16 + lm) * HR + ro];
                const bf16x8 al1 = *(const bf16x8*)&Hlo[(1 * 16 + lm) * HR + ro];
                const bf16x8 al2 = *(const bf16x8*)&Hlo[(2 * 16 + lm) * HR + ro];
                #pragma unroll
                for (int j = 0; j < 2; ++j) {
                    const __bf16* pj = j ? p1w : p0w;
                    const bf16x8 bh = *(const bf16x8*)(pj + ks * 8);
                    const bf16x8 bl = *(const bf16x8*)(pj + 32 + ks * 8);
                    acc[0][j] = MFMA(ah0, bh, acc[0][j]);
                    acc[0][j] = MFMA(ah0, bl, acc[0][j]);
                    acc[0][j] = MFMA(al0, bh, acc[0][j]);
                    acc[1][j] = MFMA(ah1, bh, acc[1][j]);
                    acc[1][j] = MFMA(ah1, bl, acc[1][j]);
                    acc[1][j] = MFMA(al1, bh, acc[1][j]);
                    acc[2][j] = MFMA(ah2, bh, acc[2][j]);
                    acc[2][j] = MFMA(ah2, bl, acc[2][j]);
                    acc[2][j] = MFMA(al2, bh, acc[2][j]);
                    acc[3][j] = MFMA(ah3, bh, acc[3][j]);
                    acc[3][j] = MFMA(ah3, bl, acc[3][j]);
                }
            }
            __syncthreads();

            const float2 bb = bh2[l * 64];
            #pragma unroll
            for (int r = 0; r < 4; ++r) {
                const int p = lq * 4 + r;
                float h[2][4];
                #pragma unroll
                for (int j = 0; j < 2; ++j) {
                    const float zv  = acc[0][j][r] + (j ? bb.y : bb.x);
                    const float zx  = acc[1][j][r];
                    const float zt  = acc[2][j][r];
                    const float zxx = acc[3][j][r];
                    const float y = fast_tanh(zv);
                    const float d = 1.f - y * y;
                    h[j][0] = y;
                    h[j][1] = d * zx;
                    h[j][2] = d * zt;
                    h[j][3] = fmaf(d, zxx, -2.f * y * d * zx * zx);
                }
                Hhi[(0 * 16 + p) * HR + wc] = pack_hi(h[0][0], h[1][0]);
                Hhi[(1 * 16 + p) * HR + wc] = pack_hi(h[0][1], h[1][1]);
                Hhi[(2 * 16 + p) * HR + wc] = pack_hi(h[0][2], h[1][2]);
                Hhi[(3 * 16 + p) * HR + wc] = pack_hi(h[0][3], h[1][3]);
                Hlo[(0 * 16 + p) * HR + wc] = pack_lo(h[0][0], h[1][0]);
                Hlo[(1 * 16 + p) * HR + wc] = pack_lo(h[0][1], h[1][1]);
                Hlo[(2 * 16 + p) * HR + wc] = pack_lo(h[0][2], h[1][2]);
            }
            p0w += 32768; p1w += 32768;
            __syncthreads();
        }
    } else {
        // ================= value-only path =================
        for (int l = 0; l < 7; ++l) {
            f32x4 acc[4][2];
            #pragma unroll
            for (int mt = 0; mt < 4; ++mt)
                #pragma unroll
                for (int j = 0; j < 2; ++j) acc[mt][j] = (f32x4){0.f, 0.f, 0.f, 0.f};

            #pragma unroll
            for (int ks = 0; ks < 4; ++ks) {
                const int ro = ks * 16 + lq * 4;
                bf16x8 ah[4], al[4];
                #pragma unroll
                for (int mt = 0; mt < 4; ++mt) {
                    ah[mt] = *(const bf16x8*)&Hhi[(mt * 16 + lm) * HR + ro];
                    al[mt] = *(const bf16x8*)&Hlo[(mt * 16 + lm) * HR + ro];
                }
                #pragma unroll
                for (int j = 0; j < 2; ++j) {
                    const __bf16* pj = j ? p1w : p0w;
                    const bf16x8 bh = *(const bf16x8*)(pj + ks * 8);
                    const bf16x8 bl = *(const bf16x8*)(pj + 32 + ks * 8);
                    #pragma unroll
                    for (int mt = 0; mt < 4; ++mt) {
                        acc[mt][j] = MFMA(ah[mt], bh, acc[mt][j]);
                        acc[mt][j] = MFMA(ah[mt], bl, acc[mt][j]);
                        acc[mt][j] = MFMA(al[mt], bh, acc[mt][j]);
                    }
                }
            }
            __syncthreads();

            const float2 bb = bh2[l * 64];
            #pragma unroll
            for (int mt = 0; mt < 4; ++mt) {
                #pragma unroll
                for (int r = 0; r < 4; ++r) {
                    const int p = mt * 16 + lq * 4 + r;
                    const float ya = fast_tanh(acc[mt][0][r] + bb.x);
                    const float yb = fast_tanh(acc[mt][1][r] + bb.y);
                    Hhi[p * HR + wc] = pack_hi(ya, yb);
                    Hlo[p * HR + wc] = pack_lo(ya, yb);
                }
            }
            p0w += 32768; p1w += 32768;
            __syncthreads();
        }
    }

    // ---- output layer: 64 dots of length 128 ----
    {
        const int st = tid & 63;
        const int ch = tid >> 6;      // 16 dwords (32 channels) per chunk
        const int cb = ch * 16;
        float part = 0.f;
        #pragma unroll
        for (int c8 = 0; c8 < 4; ++c8) {
            const bf16x8 hv = *(const bf16x8*)&Hhi[st * HR + cb + c8 * 4];
            const bf16x8 lv = *(const bf16x8*)&Hlo[st * HR + cb + c8 * 4];
            const float4 w1 = *(const float4*)&Wout[cb * 2 + c8 * 8];
            const float4 w2 = *(const float4*)&Wout[cb * 2 + c8 * 8 + 4];
            part = fmaf((float)hv[0] + (float)lv[0], w1.x, part);
            part = fmaf((float)hv[1] + (float)lv[1], w1.y, part);
            part = fmaf((float)hv[2] + (float)lv[2], w1.z, part);
            part = fmaf((float)hv[3] + (float)lv[3], w1.w, part);
            part = fmaf((float)hv[4] + (float)lv[4], w2.x, part);
            part = fmaf((float)hv[5] + (float)lv[5], w2.y, part);
            part = fmaf((float)hv[6] + (float)lv[6], w2.z, part);
            part = fmaf((float)hv[7] + (float)lv[7], w2.w, part);
        }
        pbuf[ch * 64 + st] = part;
    }
    __syncthreads();
    if (tid < 64)
        dots[tid] = pbuf[tid] + pbuf[64 + tid] + pbuf[128 + tid] + pbuf[192 + tid];
    __syncthreads();
    if (!isv) {
        if (tid < 16) {
            const float u = dots[tid] + bout[0];
            out[8192 + blk * 16 + tid] =
                dots[32 + tid] + u * dots[16 + tid] - NU_F * dots[48 + tid];
        }
    } else {
        if (tid < 64) out[(blk - 8192) * 64 + tid] = dots[tid] + bout[0];
    }
}

extern "C" void kernel_launch(void* const* d_in, const int* in_sizes, int n_in,
                              void* d_out, int out_size, void* d_ws, size_t ws_size,
                              hipStream_t stream) {
    (void)in_sizes; (void)n_in; (void)ws_size; (void)out_size;
    const float* xf   = (const float*)d_in[0];
    const float* x0   = (const float*)d_in[1];
    const float* xbl  = (const float*)d_in[2];
    const float* xbr  = (const float*)d_in[3];
    const float* Win  = (const float*)d_in[4];
    const float* bin  = (const float*)d_in[5];
    const float* Whid = (const float*)d_in[6];
    const float* bhid = (const float*)d_in[7];
    const float* Wout = (const float*)d_in[8];
    const float* bout = (const float*)d_in[9];
    float* out = (float*)d_out;

    __bf16* wcf = (__bf16*)d_ws;   // 7*128*128*2 bf16 = 448 KiB

    hipLaunchKernelGGL(prep_wfrag, dim3(114688 / 256), dim3(256), 0, stream,
                       Whid, wcf);
    hipLaunchKernelGGL(pinn_fused, dim3(8192 + 128), dim3(256), 0, stream,
                       xf, x0, xbl, xbr, Win, bin, bhid, Wout, bout, wcf, out);
}

// Round 4
// 409.620 us; speedup vs baseline: 1.9613x; 1.9613x over previous
//
#include <hip/hip_runtime.h>
#include <math.h>

#define NU_F 0.0031830988618379067f

typedef __bf16 bf16x8 __attribute__((ext_vector_type(8)));
typedef float  f32x4  __attribute__((ext_vector_type(4)));

__device__ __forceinline__ float fast_tanh(float z) {
    float e = __expf(2.0f * z);
    return 1.0f - 2.0f / (e + 1.0f);
}

// Pack truncated-bf16 hi halves of (a,b) -> one u32: {b.hi16, a.hi16}
__device__ __forceinline__ unsigned pack_hi(float a, float b) {
    return __builtin_amdgcn_perm(__float_as_uint(b), __float_as_uint(a), 0x07060302u);
}
// Pack bf16(lo) of (a,b) where lo = v - trunc16(v)
__device__ __forceinline__ unsigned pack_lo(float a, float b) {
    float ra = a - __uint_as_float(__float_as_uint(a) & 0xffff0000u);
    float rb = b - __uint_as_float(__float_as_uint(b) & 0xffff0000u);
    __bf16 la = (__bf16)ra, lb = (__bf16)rb;
    unsigned ua = (unsigned)*(unsigned short*)&la;
    unsigned ub = (unsigned)*(unsigned short*)&lb;
    return __builtin_amdgcn_perm(ub, ua, 0x05040100u);
}

// ---------------------------------------------------------------------------
// Prep: W_hid fp32 [7][128(k)][128(c)] -> bf16 hi/lo B-fragments, FRAGMENT-
// MAJOR so each wave-load is one coalesced 1 KiB block (lane-contiguous):
//   fid = ((l*8 + nt)*2 + hl)*4 + ks          (fragment id, 512 bf16 each)
//   element = fid*512 + lane*8 + jj
//   k = ks*32 + q*8 + jj, lane = q*16 + nn
//   channel map: nt = ((c>>5)<<1)|(c&1), nn = (c>>1)&15  ->  c = wv*32+nn*2+j
// ---------------------------------------------------------------------------
__global__ void prep_wfrag(const float* __restrict__ Whid, __bf16* __restrict__ wcf)
{
    int t = blockIdx.x * 256 + threadIdx.x;   // 0 .. 114687
    const int l = t >> 14;
    const int r = t & 16383;
    const int k = r >> 7;
    const int c = r & 127;
    const float v = Whid[t];
    const __bf16 hi = (__bf16)v;
    const __bf16 lo = (__bf16)(v - (float)hi);
    const int ks = k >> 5, q = (k >> 3) & 3, jj = k & 7;
    const int nt = ((c >> 5) << 1) | (c & 1);
    const int nn = (c >> 1) & 15;
    const int lane = q * 16 + nn;
    const int base = (((l * 8 + nt) * 8) + ks) * 512 + lane * 8 + jj;  // hl=0
    wcf[base]        = hi;
    wcf[base + 2048] = lo;                                             // hl=1
}

// ---------------------------------------------------------------------------
// Fused kernel. Blocks 0..8191: 16 deriv points (jet states v,vx,vt,vxx as
// 4 M-tiles). Blocks 8192..8319: 64 value-only points (4 M-tiles of points).
// H in LDS as packed u32 rows [64][68] (64 k-dwords + 4 pad), hi and lo.
// GEMM: Z[row][c] = sum_k H[row][k]*W[k][c], mfma_f32_16x16x32_bf16,
// hi/lo split (3 terms; vxx state uses 2 -- its lo rows stay zero).
// Epilogue: D col = lane&15 -> channel pair (wv*32+lm*2 + {0,1}) -> packed
// b32 writes at dword col wv*16+lm (lane-stride 1: conflict-free).
// ---------------------------------------------------------------------------
#define HR 68

#define MFMA(A, B, C) __builtin_amdgcn_mfma_f32_16x16x32_bf16((A), (B), (C), 0, 0, 0)

__global__ __launch_bounds__(256, 4)
void pinn_fused(const float* __restrict__ xf,
                const float* __restrict__ x0,  const float* __restrict__ xbl,
                const float* __restrict__ xbr,
                const float* __restrict__ Win,  const float* __restrict__ bin,
                const float* __restrict__ bhid,
                const float* __restrict__ Wout, const float* __restrict__ bout,
                const __bf16* __restrict__ wcf,
                float* __restrict__ out)
{
    __shared__ unsigned Hhi[64 * HR];
    __shared__ unsigned Hlo[64 * HR];
    __shared__ float xpt[128];
    __shared__ float pbuf[256];
    __shared__ float dots[64];

    const int tid  = threadIdx.x;
    const int lane = tid & 63;
    const int wv   = tid >> 6;
    const int lm   = lane & 15;
    const int lq   = lane >> 4;
    const int blk  = blockIdx.x;
    const bool isv = (blk >= 8192);

    if (!isv) {
        if (tid < 32) xpt[tid] = xf[blk * 32 + tid];
    } else {
        const int vb = blk - 8192;
        const float* src = (vb < 64) ? (x0 + vb * 128)
                         : (vb < 96) ? (xbl + (vb - 64) * 128)
                                     : (xbr + (vb - 96) * 128);
        if (tid < 128) xpt[tid] = src[tid];
    }
    __syncthreads();

    // ---- input layer: thread owns channel pair c0=2*(tid&63) ----
    const int cp = tid & 63;
    {
        const float2 w01 = *(const float2*)&Win[cp * 2];
        const float2 w11 = *(const float2*)&Win[128 + cp * 2];
        const float2 bb  = *(const float2*)&bin[cp * 2];
        if (!isv) {
            const int p0 = (tid >> 6) * 4;
            #pragma unroll
            for (int i = 0; i < 4; ++i) {
                const int p = p0 + i;
                const float x = xpt[2 * p], tt = xpt[2 * p + 1];
                const float za = fmaf(x, w01.x, fmaf(tt, w11.x, bb.x));
                const float zb = fmaf(x, w01.y, fmaf(tt, w11.y, bb.y));
                const float ya = fast_tanh(za), yb = fast_tanh(zb);
                const float da = 1.f - ya * ya, db = 1.f - yb * yb;
                const float v1a = da * w01.x, v1b = db * w01.y;
                const float v2a = da * w11.x, v2b = db * w11.y;
                const float v3a = -2.f * ya * da * w01.x * w01.x;
                const float v3b = -2.f * yb * db * w01.y * w01.y;
                Hhi[(0 * 16 + p) * HR + cp] = pack_hi(ya, yb);
                Hhi[(1 * 16 + p) * HR + cp] = pack_hi(v1a, v1b);
                Hhi[(2 * 16 + p) * HR + cp] = pack_hi(v2a, v2b);
                Hhi[(3 * 16 + p) * HR + cp] = pack_hi(v3a, v3b);
                Hlo[(0 * 16 + p) * HR + cp] = pack_lo(ya, yb);
                Hlo[(1 * 16 + p) * HR + cp] = pack_lo(v1a, v1b);
                Hlo[(2 * 16 + p) * HR + cp] = pack_lo(v2a, v2b);
                Hlo[(3 * 16 + p) * HR + cp] = 0u;   // stays 0 all layers
            }
        } else {
            const int p0 = (tid >> 6) * 16;
            #pragma unroll
            for (int i = 0; i < 16; ++i) {
                const int p = p0 + i;
                const float x = xpt[2 * p], tt = xpt[2 * p + 1];
                const float za = fmaf(x, w01.x, fmaf(tt, w11.x, bb.x));
                const float zb = fmaf(x, w01.y, fmaf(tt, w11.y, bb.y));
                const float ya = fast_tanh(za), yb = fast_tanh(zb);
                Hhi[p * HR + cp] = pack_hi(ya, yb);
                Hlo[p * HR + cp] = pack_lo(ya, yb);
            }
        }
    }
    __syncthreads();

    // B-fragment pointers (coalesced: lane*8 within each 512-elem fragment).
    // nt stride = 4096 elem, hi->lo = +2048 elem, ks stride = 512 elem,
    // layer stride = 32768 elem.
    const __bf16* pb0h = wcf + (wv * 2 + 0) * 4096 + lane * 8;
    const __bf16* pb0l = pb0h + 2048;
    const __bf16* pb1h = wcf + (wv * 2 + 1) * 4096 + lane * 8;
    const __bf16* pb1l = pb1h + 2048;
    const float2* bh2 = (const float2*)bhid + (wv * 16 + lm);
    const int wc = wv * 16 + lm;   // epilogue dword column

    if (!isv) {
        // ================= derivative path =================
        for (int l = 0; l < 7; ++l) {
            f32x4 acc[4][2];
            #pragma unroll
            for (int s = 0; s < 4; ++s)
                #pragma unroll
                for (int j = 0; j < 2; ++j) acc[s][j] = (f32x4){0.f, 0.f, 0.f, 0.f};

            #pragma unroll
            for (int ks = 0; ks < 4; ++ks) {
                const int ro = ks * 16 + lq * 4;
                const bf16x8 ah0 = *(const bf16x8*)&Hhi[(0 * 16 + lm) * HR + ro];
                const bf16x8 ah1 = *(const bf16x8*)&Hhi[(1 * 16 + lm) * HR + ro];
                const bf16x8 ah2 = *(const bf16x8*)&Hhi[(2 * 16 + lm) * HR + ro];
                const bf16x8 ah3 = *(const bf16x8*)&Hhi[(3 * 16 + lm) * HR + ro];
                const bf16x8 al0 = *(const bf16x8*)&Hlo[(0 * 16 + lm) * HR + ro];
                const bf16x8 al1 = *(const bf16x8*)&Hlo[(1 * 16 + lm) * HR + ro];
                const bf16x8 al2 = *(const bf16x8*)&Hlo[(2 * 16 + lm) * HR + ro];
                const bf16x8 bh0 = *(const bf16x8*)(pb0h + ks * 512);
                const bf16x8 bl0 = *(const bf16x8*)(pb0l + ks * 512);
                const bf16x8 bh1 = *(const bf16x8*)(pb1h + ks * 512);
                const bf16x8 bl1 = *(const bf16x8*)(pb1l + ks * 512);
                acc[0][0] = MFMA(ah0, bh0, acc[0][0]);
                acc[0][0] = MFMA(ah0, bl0, acc[0][0]);
                acc[0][0] = MFMA(al0, bh0, acc[0][0]);
                acc[1][0] = MFMA(ah1, bh0, acc[1][0]);
                acc[1][0] = MFMA(ah1, bl0, acc[1][0]);
                acc[1][0] = MFMA(al1, bh0, acc[1][0]);
                acc[2][0] = MFMA(ah2, bh0, acc[2][0]);
                acc[2][0] = MFMA(ah2, bl0, acc[2][0]);
                acc[2][0] = MFMA(al2, bh0, acc[2][0]);
                acc[3][0] = MFMA(ah3, bh0, acc[3][0]);
                acc[3][0] = MFMA(ah3, bl0, acc[3][0]);
                acc[0][1] = MFMA(ah0, bh1, acc[0][1]);
                acc[0][1] = MFMA(ah0, bl1, acc[0][1]);
                acc[0][1] = MFMA(al0, bh1, acc[0][1]);
                acc[1][1] = MFMA(ah1, bh1, acc[1][1]);
                acc[1][1] = MFMA(ah1, bl1, acc[1][1]);
                acc[1][1] = MFMA(al1, bh1, acc[1][1]);
                acc[2][1] = MFMA(ah2, bh1, acc[2][1]);
                acc[2][1] = MFMA(ah2, bl1, acc[2][1]);
                acc[2][1] = MFMA(al2, bh1, acc[2][1]);
                acc[3][1] = MFMA(ah3, bh1, acc[3][1]);
                acc[3][1] = MFMA(ah3, bl1, acc[3][1]);
            }
            __syncthreads();

            const float2 bb = bh2[l * 64];
            #pragma unroll
            for (int r = 0; r < 4; ++r) {
                const int p = lq * 4 + r;
                float h[2][4];
                #pragma unroll
                for (int j = 0; j < 2; ++j) {
                    const float zv  = acc[0][j][r] + (j ? bb.y : bb.x);
                    const float zx  = acc[1][j][r];
                    const float zt  = acc[2][j][r];
                    const float zxx = acc[3][j][r];
                    const float y = fast_tanh(zv);
                    const float d = 1.f - y * y;
                    h[j][0] = y;
                    h[j][1] = d * zx;
                    h[j][2] = d * zt;
                    h[j][3] = fmaf(d, zxx, -2.f * y * d * zx * zx);
                }
                Hhi[(0 * 16 + p) * HR + wc] = pack_hi(h[0][0], h[1][0]);
                Hhi[(1 * 16 + p) * HR + wc] = pack_hi(h[0][1], h[1][1]);
                Hhi[(2 * 16 + p) * HR + wc] = pack_hi(h[0][2], h[1][2]);
                Hhi[(3 * 16 + p) * HR + wc] = pack_hi(h[0][3], h[1][3]);
                Hlo[(0 * 16 + p) * HR + wc] = pack_lo(h[0][0], h[1][0]);
                Hlo[(1 * 16 + p) * HR + wc] = pack_lo(h[0][1], h[1][1]);
                Hlo[(2 * 16 + p) * HR + wc] = pack_lo(h[0][2], h[1][2]);
            }
            pb0h += 32768; pb0l += 32768; pb1h += 32768; pb1l += 32768;
            __syncthreads();
        }
    } else {
        // ================= value-only path =================
        for (int l = 0; l < 7; ++l) {
            f32x4 acc[4][2];
            #pragma unroll
            for (int mt = 0; mt < 4; ++mt)
                #pragma unroll
                for (int j = 0; j < 2; ++j) acc[mt][j] = (f32x4){0.f, 0.f, 0.f, 0.f};

            #pragma unroll
            for (int ks = 0; ks < 4; ++ks) {
                const int ro = ks * 16 + lq * 4;
                bf16x8 ah[4], al[4];
                #pragma unroll
                for (int mt = 0; mt < 4; ++mt) {
                    ah[mt] = *(const bf16x8*)&Hhi[(mt * 16 + lm) * HR + ro];
                    al[mt] = *(const bf16x8*)&Hlo[(mt * 16 + lm) * HR + ro];
                }
                const bf16x8 bh0 = *(const bf16x8*)(pb0h + ks * 512);
                const bf16x8 bl0 = *(const bf16x8*)(pb0l + ks * 512);
                const bf16x8 bh1 = *(const bf16x8*)(pb1h + ks * 512);
                const bf16x8 bl1 = *(const bf16x8*)(pb1l + ks * 512);
                #pragma unroll
                for (int mt = 0; mt < 4; ++mt) {
                    acc[mt][0] = MFMA(ah[mt], bh0, acc[mt][0]);
                    acc[mt][0] = MFMA(ah[mt], bl0, acc[mt][0]);
                    acc[mt][0] = MFMA(al[mt], bh0, acc[mt][0]);
                    acc[mt][1] = MFMA(ah[mt], bh1, acc[mt][1]);
                    acc[mt][1] = MFMA(ah[mt], bl1, acc[mt][1]);
                    acc[mt][1] = MFMA(al[mt], bh1, acc[mt][1]);
                }
            }
            __syncthreads();

            const float2 bb = bh2[l * 64];
            #pragma unroll
            for (int mt = 0; mt < 4; ++mt) {
                #pragma unroll
                for (int r = 0; r < 4; ++r) {
                    const int p = mt * 16 + lq * 4 + r;
                    const float ya = fast_tanh(acc[mt][0][r] + bb.x);
                    const float yb = fast_tanh(acc[mt][1][r] + bb.y);
                    Hhi[p * HR + wc] = pack_hi(ya, yb);
                    Hlo[p * HR + wc] = pack_lo(ya, yb);
                }
            }
            pb0h += 32768; pb0l += 32768; pb1h += 32768; pb1l += 32768;
            __syncthreads();
        }
    }

    // ---- output layer: 64 dots of length 128 ----
    {
        const int st = tid & 63;
        const int ch = tid >> 6;      // 16 dwords (32 channels) per chunk
        const int cb = ch * 16;
        float part = 0.f;
        #pragma unroll
        for (int c8 = 0; c8 < 4; ++c8) {
            const bf16x8 hv = *(const bf16x8*)&Hhi[st * HR + cb + c8 * 4];
            const bf16x8 lv = *(const bf16x8*)&Hlo[st * HR + cb + c8 * 4];
            const float4 w1 = *(const float4*)&Wout[cb * 2 + c8 * 8];
            const float4 w2 = *(const float4*)&Wout[cb * 2 + c8 * 8 + 4];
            part = fmaf((float)hv[0] + (float)lv[0], w1.x, part);
            part = fmaf((float)hv[1] + (float)lv[1], w1.y, part);
            part = fmaf((float)hv[2] + (float)lv[2], w1.z, part);
            part = fmaf((float)hv[3] + (float)lv[3], w1.w, part);
            part = fmaf((float)hv[4] + (float)lv[4], w2.x, part);
            part = fmaf((float)hv[5] + (float)lv[5], w2.y, part);
            part = fmaf((float)hv[6] + (float)lv[6], w2.z, part);
            part = fmaf((float)hv[7] + (float)lv[7], w2.w, part);
        }
        pbuf[ch * 64 + st] = part;
    }
    __syncthreads();
    if (tid < 64)
        dots[tid] = pbuf[tid] + pbuf[64 + tid] + pbuf[128 + tid] + pbuf[192 + tid];
    __syncthreads();
    if (!isv) {
        if (tid < 16) {
            const float u = dots[tid] + bout[0];
            out[8192 + blk * 16 + tid] =
                dots[32 + tid] + u * dots[16 + tid] - NU_F * dots[48 + tid];
        }
    } else {
        if (tid < 64) out[(blk - 8192) * 64 + tid] = dots[tid] + bout[0];
    }
}

extern "C" void kernel_launch(void* const* d_in, const int* in_sizes, int n_in,
                              void* d_out, int out_size, void* d_ws, size_t ws_size,
                              hipStream_t stream) {
    (void)in_sizes; (void)n_in; (void)ws_size; (void)out_size;
    const float* xf   = (const float*)d_in[0];
    const float* x0   = (const float*)d_in[1];
    const float* xbl  = (const float*)d_in[2];
    const float* xbr  = (const float*)d_in[3];
    const float* Win  = (const float*)d_in[4];
    const float* bin  = (const float*)d_in[5];
    const float* Whid = (const float*)d_in[6];
    const float* bhid = (const float*)d_in[7];
    const float* Wout = (const float*)d_in[8];
    const float* bout = (const float*)d_in[9];
    float* out = (float*)d_out;

    __bf16* wcf = (__bf16*)d_ws;   // 7*128*128*2 bf16 = 448 KiB

    hipLaunchKernelGGL(prep_wfrag, dim3(114688 / 256), dim3(256), 0, stream,
                       Whid, wcf);
    hipLaunchKernelGGL(pinn_fused, dim3(8192 + 128), dim3(256), 0, stream,
                       xf, x0, xbl, xbr, Win, bin, bhid, Wout, bout, wcf, out);
}